// Round 11
// baseline (319.048 us; speedup 1.0000x reference)
//
#include <hip/hip_runtime.h>
#include <hip/hip_bf16.h>
#include <math.h>

// Cosine attention, n=8, L=S=2048, d=v=64.
// out0 = softmax((q^·k^T)/8) @ V  [8,2048,64]; out1 = softmax scores [8,2048,2048]
// |score| <= 1/8 (unit vectors) -> exp in [0.88,1.13] -> no running max needed.
//
// v11 = r8 structure widened to 32 L-rows/block (R=2) to halve L2 traffic.
//   Audit (r10): every block reads full K[n]+Vt[n] (4MB); 1024 blocks -> 4.3GB
//   of L2->CU traffic ~= 125us at the 34.5TB/s L2 ceiling ~= the measured
//   103us. The kernel is L2-BW-bound, which is why HBM/VALU/MFMA all idle and
//   why scheduling tweaks (r9/r10) were flat.
//   R=2: each wave runs QK for two row-groups (l = g*16+m16) off the SAME K
//   fragments, and PV reuses the SAME bv loads for both groups -> K/Vt bytes
//   per block unchanged, blocks halved (512) -> 2.15GB L2 -> ~62us floor.
//   Stash goes fp8-e4m3 (hw cvt_pk roundtrip) to keep VGPR<=128 / 2 blocks/CU:
//   score quantization err ~1.5e-5 << current 4.9e-4 absmax (bf16 PV path,
//   unchanged: rowsum f32, PV operands bf16 as before). bv dbuf dropped (r8
//   ran without it). Mask staging covers 32 rows, still 512B-run coalesced;
//   epilogue = two 16-row halves of r8's transposed coalesced store.
// Mask arrives as int32 (harness materializes bool as int) — NOT bytes.

typedef __bf16 bf16x8 __attribute__((ext_vector_type(8)));
typedef __bf16 bf16x4 __attribute__((ext_vector_type(4)));
typedef float f32x4 __attribute__((ext_vector_type(4)));

#define NB 8
#define LL 2048
#define SS 2048
#define DD 64

// fp8 pack/unpack (on-chip roundtrip; gfx950 fp8 = OCP e4m3)
#if __has_builtin(__builtin_amdgcn_cvt_pk_fp8_f32) && __has_builtin(__builtin_amdgcn_cvt_pk_f32_fp8)
static __device__ __forceinline__ unsigned pack4_fp8(float a, float b, float c, float d) {
  int p = 0;
  p = __builtin_amdgcn_cvt_pk_fp8_f32(a, b, p, false);
  p = __builtin_amdgcn_cvt_pk_fp8_f32(c, d, p, true);
  return (unsigned)p;
}
static __device__ __forceinline__ float4 unpack4_fp8(unsigned u) {
  auto lo = __builtin_amdgcn_cvt_pk_f32_fp8((int)u, false);
  auto hi = __builtin_amdgcn_cvt_pk_f32_fp8((int)u, true);
  return make_float4(lo[0], lo[1], hi[0], hi[1]);
}
#else
#include <hip/hip_fp8.h>
static __device__ __forceinline__ unsigned pack4_fp8(float a, float b, float c, float d) {
  union { unsigned u; __hip_fp8_storage_t b4[4]; } r;
  r.b4[0] = __hip_cvt_float_to_fp8(a, __HIP_SATFINITE, __HIP_E4M3);
  r.b4[1] = __hip_cvt_float_to_fp8(b, __HIP_SATFINITE, __HIP_E4M3);
  r.b4[2] = __hip_cvt_float_to_fp8(c, __HIP_SATFINITE, __HIP_E4M3);
  r.b4[3] = __hip_cvt_float_to_fp8(d, __HIP_SATFINITE, __HIP_E4M3);
  return r.u;
}
static __device__ __forceinline__ float4 unpack4_fp8(unsigned u) {
  union { unsigned u; __hip_fp8_storage_t b4[4]; } r;
  r.u = u;
  return make_float4(
      (float)__hip_cvt_fp8_to_halfraw(r.b4[0], __HIP_E4M3).data == 0 ? 0.f : (float)__half(__hip_cvt_fp8_to_halfraw(r.b4[0], __HIP_E4M3)),
      (float)__half(__hip_cvt_fp8_to_halfraw(r.b4[1], __HIP_E4M3)),
      (float)__half(__hip_cvt_fp8_to_halfraw(r.b4[2], __HIP_E4M3)),
      (float)__half(__hip_cvt_fp8_to_halfraw(r.b4[3], __HIP_E4M3)));
}
#endif

// ---- prep 1: L2-normalize Q (fold 1/8) and K rows, cast to bf16 ----
__global__ __launch_bounds__(256) void prep_norm(const float* __restrict__ q,
                                                 const float* __restrict__ k,
                                                 __bf16* __restrict__ Qb,
                                                 __bf16* __restrict__ Kb) {
  int w = threadIdx.x >> 6, lane = threadIdx.x & 63;
  int r = blockIdx.x * 4 + w;
  const float* src;
  __bf16* dst;
  float extra;
  if (r < NB * LL) {
    src = q + (size_t)r * DD;
    dst = Qb + (size_t)r * DD;
    extra = 0.125f;  // fold 1/sqrt(64) into Q
  } else {
    int rk = r - NB * LL;
    src = k + (size_t)rk * DD;
    dst = Kb + (size_t)rk * DD;
    extra = 1.0f;
  }
  float x = src[lane];
  float ss = x * x;
  ss += __shfl_xor(ss, 1);
  ss += __shfl_xor(ss, 2);
  ss += __shfl_xor(ss, 4);
  ss += __shfl_xor(ss, 8);
  ss += __shfl_xor(ss, 16);
  ss += __shfl_xor(ss, 32);
  float nrm = sqrtf(ss);
  float sc = extra / fmaxf(nrm, 1e-12f);
  dst[lane] = (__bf16)(x * sc);
}

// ---- prep 2: V [n][s][v] f32 -> Vt [n][v][s] bf16 (64x64 LDS tiles) ----
__global__ __launch_bounds__(256) void prep_vt(const float* __restrict__ v,
                                               __bf16* __restrict__ Vt) {
  __shared__ __bf16 tile[64][72];
  int n = blockIdx.y;
  int s0 = blockIdx.x * 64;
  int t = threadIdx.x;
#pragma unroll
  for (int it = 0; it < 4; ++it) {
    int idx = t + it * 256;
    int s = idx >> 4, c = idx & 15;
    float4 f = *(const float4*)(v + ((size_t)(n * SS + s0 + s)) * DD + c * 4);
    tile[s][c * 4 + 0] = (__bf16)f.x;
    tile[s][c * 4 + 1] = (__bf16)f.y;
    tile[s][c * 4 + 2] = (__bf16)f.z;
    tile[s][c * 4 + 3] = (__bf16)f.w;
  }
  __syncthreads();
#pragma unroll
  for (int it = 0; it < 4; ++it) {
    int idx = t + it * 256;
    int vv = idx >> 4, c = idx & 15;
    bf16x4 o;
    o[0] = tile[c * 4 + 0][vv];
    o[1] = tile[c * 4 + 1][vv];
    o[2] = tile[c * 4 + 2][vv];
    o[3] = tile[c * 4 + 3][vv];
    *(bf16x4*)(Vt + ((size_t)(n * DD + vv)) * SS + s0 + c * 4) = o;
  }
}

static __device__ __forceinline__ unsigned packmask(int4 m) {
  return (unsigned)((m.x != 0) | ((m.y != 0) << 8) | ((m.z != 0) << 16) |
                    ((m.w != 0) << 24));
}

// ---- main: 32 L-rows per block (two 16-row groups), 8 waves (512 thr) ----
// Wave w: QK for s-cols [w*16,w*16+16) of each 128-chunk, BOTH row groups off
// the same K frags. Per-lane: (l = l0 + g*16 + m16, s = sc + w*16 + quad*4+r).
// PV split (vg = w&3, s-half = (w>>2)*64); bv reused for both groups.
// LDS layout (bytes):
//   [0,17408)      e_lds   [2][32][136] bf16    } dead after main loop
//   [17408,25856)  mb_lds  [2][32][33]  u32     }
//   [25856,26880)  rs_lds  [8][32]      f32     } dead after out_val
//   [26880,35584)  acc_red [4][32][17]  f32     }
//   [35584,35712)  inv_row [32]         f32     live through epilogue
//   epilogue ep[16][130] u32 (8320B) aliases [0,8320)
__global__ __launch_bounds__(512, 4) void attn_main(const __bf16* __restrict__ Qb,
                                                    const __bf16* __restrict__ Kb,
                                                    const __bf16* __restrict__ Vt,
                                                    const int* __restrict__ mask,
                                                    float* __restrict__ out_val,
                                                    float* __restrict__ out_score) {
  __shared__ __align__(16) char smem[35712];
  __bf16 (*e_lds)[32][136] = (__bf16(*)[32][136])(smem);
  unsigned (*mb_lds)[32][33] = (unsigned(*)[32][33])(smem + 17408);
  float (*rs_lds)[32] = (float(*)[32])(smem + 25856);
  float (*acc_red)[32][17] = (float(*)[32][17])(smem + 26880);
  float* inv_row = (float*)(smem + 35584);
  unsigned (*ep)[130] = (unsigned(*)[130])(smem);

  const int n = blockIdx.y;
  const int l0 = blockIdx.x * 32;

  const int t = threadIdx.x;
  const int w = t >> 6;
  const int lane = t & 63;
  const int m16 = lane & 15;
  const int quad = lane >> 4;
  const int vg = w & 3;            // PV v-group
  const int sh = (w >> 2) * 64;    // PV s-half within chunk

  // Q fragments for both row groups (B operand of transposed QK)
  const __bf16* qrowA = Qb + ((size_t)(n * LL + l0 + m16)) * DD;
  const __bf16* qrowB = qrowA + (size_t)16 * DD;
  bf16x8 aqA0 = *(const bf16x8*)(qrowA + quad * 8);
  bf16x8 aqA1 = *(const bf16x8*)(qrowA + 32 + quad * 8);
  bf16x8 aqB0 = *(const bf16x8*)(qrowB + quad * 8);
  bf16x8 aqB1 = *(const bf16x8*)(qrowB + 32 + quad * 8);

  const __bf16* kbase = Kb + (size_t)n * SS * DD;
  const __bf16* krow0 = kbase + (size_t)(w * 16 + m16) * DD;
  const __bf16* vrow = Vt + ((size_t)(n * DD + vg * 16 + m16)) * SS + sh;

  // coalesced mask staging: thread t -> row t>>4 (0..31), cols (t&15)*8..+8
  const int srow = t >> 4;
  const int sc2 = (t & 15) * 2;  // mb_lds word col base
  const int* mgbase = mask + ((size_t)(n * LL + l0 + srow)) * SS + (t & 15) * 8;

  f32x4 acc_oA = {0.f, 0.f, 0.f, 0.f};
  f32x4 acc_oB = {0.f, 0.f, 0.f, 0.f};
  float rsumA = 0.f, rsumB = 0.f;
  unsigned stashA[16], stashB[16];  // fp8x4 per chunk per group (static idx)

  // mask reg ring, depth 2 (slot p holds m with parity p); m(c+3) loaded at c
  int4 mra[2], mrb[2];
  {
    int4 m0a = *(const int4*)(mgbase + 0);
    int4 m0b = *(const int4*)(mgbase + 4);
    mra[1] = *(const int4*)(mgbase + 1 * 128);
    mrb[1] = *(const int4*)(mgbase + 1 * 128 + 4);
    mra[0] = *(const int4*)(mgbase + 2 * 128);
    mrb[0] = *(const int4*)(mgbase + 2 * 128 + 4);
    mb_lds[0][srow][sc2 + 0] = packmask(m0a);
    mb_lds[0][srow][sc2 + 1] = packmask(m0b);
  }
  // K ping-pong
  bf16x8 kpa0, kpa1, kpb0, kpb1;
  kpa0 = *(const bf16x8*)(krow0 + quad * 8);
  kpa1 = *(const bf16x8*)(krow0 + 32 + quad * 8);

  asm volatile("s_waitcnt lgkmcnt(0)" ::: "memory");
  __builtin_amdgcn_s_barrier();

#pragma unroll
  for (int c = 0; c < 16; ++c) {
    const int sc = c * 128;
    // ---- loads in consumption order ----
    // (1) bv(c): consumed this chunk post-barrier (shared by both groups)
    bf16x8 bv0 = *(const bf16x8*)(vrow + sc + quad * 8);
    bf16x8 bv1 = *(const bf16x8*)(vrow + sc + 32 + quad * 8);
    // (2) K(c+1): consumed next chunk's QK
    if (c + 1 < 16) {
      const __bf16* kr = krow0 + (size_t)(sc + 128) * DD;
      if (c & 1) {
        kpa0 = *(const bf16x8*)(kr + quad * 8);
        kpa1 = *(const bf16x8*)(kr + 32 + quad * 8);
      } else {
        kpb0 = *(const bf16x8*)(kr + quad * 8);
        kpb1 = *(const bf16x8*)(kr + 32 + quad * 8);
      }
    }
    // stage m(c+1) (loaded at chunk c-2), then refill slot with m(c+3)
    if (c + 1 < 16) {
      mb_lds[(c + 1) & 1][srow][sc2 + 0] = packmask(mra[(c + 1) & 1]);
      mb_lds[(c + 1) & 1][srow][sc2 + 1] = packmask(mrb[(c + 1) & 1]);
    }
    if (c + 3 < 16) {
      mra[(c + 1) & 1] = *(const int4*)(mgbase + (size_t)(c + 3) * 128);
      mrb[(c + 1) & 1] = *(const int4*)(mgbase + (size_t)(c + 3) * 128 + 4);
    }
    // this chunk's flags (staged at c-1, ordered by barrier c-1)
    const unsigned muA = mb_lds[c & 1][m16][w * 4 + quad];
    const unsigned muB = mb_lds[c & 1][16 + m16][w * 4 + quad];
    // QK transposed, both groups off the same K fragments
    const bf16x8 kb0 = (c & 1) ? kpb0 : kpa0;
    const bf16x8 kb1 = (c & 1) ? kpb1 : kpa1;
    f32x4 accA = {0.f, 0.f, 0.f, 0.f};
    f32x4 accB = {0.f, 0.f, 0.f, 0.f};
    accA = __builtin_amdgcn_mfma_f32_16x16x32_bf16(kb0, aqA0, accA, 0, 0, 0);
    accA = __builtin_amdgcn_mfma_f32_16x16x32_bf16(kb1, aqA1, accA, 0, 0, 0);
    accB = __builtin_amdgcn_mfma_f32_16x16x32_bf16(kb0, aqB0, accB, 0, 0, 0);
    accB = __builtin_amdgcn_mfma_f32_16x16x32_bf16(kb1, aqB1, accB, 0, 0, 0);
    const float eA0 = (muA & 0x1u) ? __expf(accA[0]) : 0.f;
    const float eA1 = (muA & 0x100u) ? __expf(accA[1]) : 0.f;
    const float eA2 = (muA & 0x10000u) ? __expf(accA[2]) : 0.f;
    const float eA3 = (muA & 0x1000000u) ? __expf(accA[3]) : 0.f;
    const float eB0 = (muB & 0x1u) ? __expf(accB[0]) : 0.f;
    const float eB1 = (muB & 0x100u) ? __expf(accB[1]) : 0.f;
    const float eB2 = (muB & 0x10000u) ? __expf(accB[2]) : 0.f;
    const float eB3 = (muB & 0x1000000u) ? __expf(accB[3]) : 0.f;
    rsumA += (eA0 + eA1) + (eA2 + eA3);
    rsumB += (eB0 + eB1) + (eB2 + eB3);
    stashA[c] = pack4_fp8(eA0, eA1, eA2, eA3);
    stashB[c] = pack4_fp8(eB0, eB1, eB2, eB3);
    bf16x4 svA, svB;
    svA[0] = (__bf16)eA0; svA[1] = (__bf16)eA1;
    svA[2] = (__bf16)eA2; svA[3] = (__bf16)eA3;
    svB[0] = (__bf16)eB0; svB[1] = (__bf16)eB1;
    svB[2] = (__bf16)eB2; svB[3] = (__bf16)eB3;
    *(bf16x4*)(&e_lds[c & 1][m16][w * 16 + quad * 4]) = svA;
    *(bf16x4*)(&e_lds[c & 1][16 + m16][w * 16 + quad * 4]) = svB;
    // LDS-only fence + raw barrier (globals stay in flight)
    asm volatile("s_waitcnt lgkmcnt(0)" ::: "memory");
    __builtin_amdgcn_s_barrier();
    // PV: both groups reuse bv (the L2-traffic win)
    bf16x8 aeA0 = *(const bf16x8*)(&e_lds[c & 1][m16][sh + quad * 8]);
    bf16x8 aeA1 = *(const bf16x8*)(&e_lds[c & 1][m16][sh + 32 + quad * 8]);
    bf16x8 aeB0 = *(const bf16x8*)(&e_lds[c & 1][16 + m16][sh + quad * 8]);
    bf16x8 aeB1 = *(const bf16x8*)(&e_lds[c & 1][16 + m16][sh + 32 + quad * 8]);
    acc_oA = __builtin_amdgcn_mfma_f32_16x16x32_bf16(aeA0, bv0, acc_oA, 0, 0, 0);
    acc_oA = __builtin_amdgcn_mfma_f32_16x16x32_bf16(aeA1, bv1, acc_oA, 0, 0, 0);
    acc_oB = __builtin_amdgcn_mfma_f32_16x16x32_bf16(aeB0, bv0, acc_oB, 0, 0, 0);
    acc_oB = __builtin_amdgcn_mfma_f32_16x16x32_bf16(aeB1, bv1, acc_oB, 0, 0, 0);
    // dbuf proofs as r8: e_lds[c&1]/mb_lds[(c+1)&1] rewritten only after the
    // barrier following their last reads.
  }

  // rowsum reduce + PV partial publish
  rsumA += __shfl_xor(rsumA, 16);
  rsumA += __shfl_xor(rsumA, 32);
  rsumB += __shfl_xor(rsumB, 16);
  rsumB += __shfl_xor(rsumB, 32);
  if (quad == 0) {
    rs_lds[w][m16] = rsumA;
    rs_lds[w][16 + m16] = rsumB;
  }
  if (w >= 4) {
#pragma unroll
    for (int r = 0; r < 4; ++r) {
      acc_red[vg][quad * 4 + r][m16] = acc_oA[r];
      acc_red[vg][16 + quad * 4 + r][m16] = acc_oB[r];
    }
  }
  __syncthreads();

  if (t < 32) {
    float tot = 0.f;
#pragma unroll
    for (int ww = 0; ww < 8; ++ww) tot += rs_lds[ww][t];
    inv_row[t] = 1.0f / tot;
  }

  // out_value: lower s-half waves combine pair partials, both groups
  if (w < 4) {
#pragma unroll
    for (int r = 0; r < 4; ++r) {
      const int rowA = quad * 4 + r;
      const int rowB = 16 + quad * 4 + r;
      float trA = 0.f, trB = 0.f;
#pragma unroll
      for (int ww = 0; ww < 8; ++ww) {
        trA += rs_lds[ww][rowA];
        trB += rs_lds[ww][rowB];
      }
      out_val[((size_t)(n * LL + l0 + rowA)) * DD + vg * 16 + m16] =
          (acc_oA[r] + acc_red[vg][rowA][m16]) / trA;
      out_val[((size_t)(n * LL + l0 + rowB)) * DD + vg * 16 + m16] =
          (acc_oB[r] + acc_red[vg][rowB][m16]) / trB;
    }
  }
  __syncthreads();  // inv_row visible; e_lds/mb/rs/acc_red dead -> ep aliases

  // ---- score epilogue: two 16-row halves, LDS transpose, coalesced stores ----
  // per (h,g): writers put fp8x4 words; readers (thread t -> row t>>5,
  // word t&31) store 512B-contiguous float4 runs per 32 lanes.
  const int erow = t >> 5;
  const int ecol = t & 31;
#pragma unroll
  for (int h = 0; h < 2; ++h) {
    const float einv = inv_row[h * 16 + erow];
    float* obase = out_score + ((size_t)(n * LL + l0 + h * 16 + erow)) * SS;
#pragma unroll
    for (int g = 0; g < 4; ++g) {
#pragma unroll
      for (int i = 0; i < 4; ++i) {
        const unsigned u = h ? stashB[g * 4 + i] : stashA[g * 4 + i];
        ep[m16][i * 32 + w * 4 + quad] = u;
      }
      asm volatile("s_waitcnt lgkmcnt(0)" ::: "memory");
      __builtin_amdgcn_s_barrier();
#pragma unroll
      for (int i = 0; i < 4; ++i) {
        const float4 e4 = unpack4_fp8(ep[erow][ecol + i * 32]);
        float4 o;
        o.x = e4.x * einv;
        o.y = e4.y * einv;
        o.z = e4.z * einv;
        o.w = e4.w * einv;
        *(float4*)(obase + g * 512 + ecol * 4 + i * 128) = o;
      }
      asm volatile("s_waitcnt lgkmcnt(0)" ::: "memory");
      __builtin_amdgcn_s_barrier();  // reads done before next group's writes
    }
  }
}

extern "C" void kernel_launch(void* const* d_in, const int* in_sizes, int n_in,
                              void* d_out, int out_size, void* d_ws, size_t ws_size,
                              hipStream_t stream) {
  const float* q = (const float*)d_in[0];
  const float* k = (const float*)d_in[1];
  const float* v = (const float*)d_in[2];
  const int* mask = (const int*)d_in[3];  // harness materializes bool as int32

  float* out_val = (float*)d_out;                       // [8,2048,64]
  float* out_score = out_val + (size_t)NB * LL * DD;    // [8,2048,2048]

  __bf16* Qb = (__bf16*)d_ws;                  // 2 MB
  __bf16* Kb = Qb + (size_t)NB * LL * DD;      // 2 MB
  __bf16* Vt = Kb + (size_t)NB * SS * DD;      // 2 MB (transposed [n][v][s])

  prep_norm<<<dim3((NB * LL * 2) / 4), dim3(256), 0, stream>>>(q, k, Qb, Kb);
  prep_vt<<<dim3(SS / 64, NB), dim3(256), 0, stream>>>(v, Vt);
  attn_main<<<dim3(LL / 32, NB), dim3(512), 0, stream>>>(Qb, Kb, Vt, mask, out_val, out_score);
}

// Round 12
// 281.212 us; speedup vs baseline: 1.1345x; 1.1345x over previous
//
#include <hip/hip_runtime.h>
#include <hip/hip_bf16.h>
#include <math.h>

// Cosine attention, n=8, L=S=2048, d=v=64.
// out0 = softmax((q^·k^T)/8) @ V  [8,2048,64]; out1 = softmax scores [8,2048,2048]
// |score| <= 1/8 (unit vectors) -> exp in [0.88,1.13] -> no running max needed.
//
// v12 = r8 attn_main VERBATIM (best measured: 99us attn / 278us total) plus:
//   - s_setprio(1) around the {QK mfma + exp} and {PV mfma} clusters. r8 runs
//     4 phase-independent blocks/CU; priority lets compute-phase waves preempt
//     other blocks' staging waves (T5: +4-7% on attn with independent blocks,
//     null only in lockstep single-block regimes).
//   - prep_norm + prep_vt fused into one launch (branch by block range).
//   Ledger (r9/r10/r11): streamed stores +28us recompute, deeper mask prefetch
//   flat (latency not binding), R=2 blew the L3 streaming footprint (FETCH
//   83->159, WRITE 135->226). All reverted. The r10 "L2-BW-bound" audit was
//   8x off (K[n]+Vt[n] = 512 KB, not 4 MB); no single pipe is saturated in r8
//   -- residue is distributed barrier/wait convoy, attacked here via setprio.
// Mask arrives as int32 (harness materializes bool as int) — NOT bytes.

typedef __bf16 bf16x8 __attribute__((ext_vector_type(8)));
typedef __bf16 bf16x4 __attribute__((ext_vector_type(4)));
typedef float f32x4 __attribute__((ext_vector_type(4)));

#define NB 8
#define LL 2048
#define SS 2048
#define DD 64
#define NORM_BLOCKS ((NB * LL * 2) / 4)
#define VT_BLOCKS (NB * (SS / 64))

// ---- fused prep: [0,8192) Q/K norm | [8192,8448) V transpose ----
__global__ __launch_bounds__(256) void prep_all(const float* __restrict__ q,
                                                const float* __restrict__ k,
                                                const float* __restrict__ v,
                                                __bf16* __restrict__ Qb,
                                                __bf16* __restrict__ Kb,
                                                __bf16* __restrict__ Vt) {
  __shared__ __bf16 tile[64][72];  // Vt branch only
  const int bid = blockIdx.x;
  const int t = threadIdx.x;

  if (bid < NORM_BLOCKS) {
    // L2-normalize Q (fold 1/8) and K rows, cast to bf16; one wave per row.
    const int w = t >> 6, lane = t & 63;
    const int r = bid * 4 + w;
    const float* src;
    __bf16* dst;
    float extra;
    if (r < NB * LL) {
      src = q + (size_t)r * DD;
      dst = Qb + (size_t)r * DD;
      extra = 0.125f;  // fold 1/sqrt(64) into Q
    } else {
      int rk = r - NB * LL;
      src = k + (size_t)rk * DD;
      dst = Kb + (size_t)rk * DD;
      extra = 1.0f;
    }
    float x = src[lane];
    float ss = x * x;
    ss += __shfl_xor(ss, 1);
    ss += __shfl_xor(ss, 2);
    ss += __shfl_xor(ss, 4);
    ss += __shfl_xor(ss, 8);
    ss += __shfl_xor(ss, 16);
    ss += __shfl_xor(ss, 32);
    float nrm = sqrtf(ss);
    float sc = extra / fmaxf(nrm, 1e-12f);
    dst[lane] = (__bf16)(x * sc);
  } else {
    // V [n][s][v] f32 -> Vt [n][v][s] bf16, 64x64 LDS tiles.
    const int vb = bid - NORM_BLOCKS;  // 0..255
    const int n = vb >> 5;
    const int s0 = (vb & 31) * 64;
#pragma unroll
    for (int it = 0; it < 4; ++it) {
      int idx = t + it * 256;
      int s = idx >> 4, c = idx & 15;
      float4 f = *(const float4*)(v + ((size_t)(n * SS + s0 + s)) * DD + c * 4);
      tile[s][c * 4 + 0] = (__bf16)f.x;
      tile[s][c * 4 + 1] = (__bf16)f.y;
      tile[s][c * 4 + 2] = (__bf16)f.z;
      tile[s][c * 4 + 3] = (__bf16)f.w;
    }
    __syncthreads();
#pragma unroll
    for (int it = 0; it < 4; ++it) {
      int idx = t + it * 256;
      int vv = idx >> 4, c = idx & 15;
      bf16x4 o;
      o[0] = tile[c * 4 + 0][vv];
      o[1] = tile[c * 4 + 1][vv];
      o[2] = tile[c * 4 + 2][vv];
      o[3] = tile[c * 4 + 3][vv];
      *(bf16x4*)(Vt + ((size_t)(n * DD + vv)) * SS + s0 + c * 4) = o;
    }
  }
}

// ---- main: 16 L-rows per block, 8 waves (512 thr), S streamed in 128-col chunks ----
__global__ __launch_bounds__(512, 4) void attn_main(const __bf16* __restrict__ Qb,
                                                    const __bf16* __restrict__ Kb,
                                                    const __bf16* __restrict__ Vt,
                                                    const int* __restrict__ mask,
                                                    float* __restrict__ out_val,
                                                    float* __restrict__ out_score) {
  __shared__ __bf16 e_lds[2][16][136];     // E chunk, row = l, col = s-in-chunk
  __shared__ unsigned mb_lds[2][16][33];   // packed mask (4 flag-bytes per uint)
  __shared__ float rs_lds[8][16];          // per-wave row-sum partials
  __shared__ float acc_red[4][16][17];     // PV partial exchange
  __shared__ float inv_row[16];            // 1/rowsum for epilogue threads
  __shared__ __bf16 ep_buf[16][520];       // epilogue transpose buffer (512+8 pad)

  const int n = blockIdx.y;
  const int l0 = blockIdx.x * 16;

  const int t = threadIdx.x;
  const int w = t >> 6;
  const int lane = t & 63;
  const int m16 = lane & 15;
  const int quad = lane >> 4;
  const int vg = w & 3;            // PV v-group
  const int sh = (w >> 2) * 64;    // PV s-half within chunk

  // Q fragment (B operand of transposed QK): B[n=m16][k=quad*8+j] = Q[l0+m16][k]
  const __bf16* qrow = Qb + ((size_t)(n * LL + l0 + m16)) * DD;
  bf16x8 aq0 = *(const bf16x8*)(qrow + quad * 8);
  bf16x8 aq1 = *(const bf16x8*)(qrow + 32 + quad * 8);

  const __bf16* kbase = Kb + (size_t)n * SS * DD;
  const __bf16* vrow = Vt + ((size_t)(n * DD + vg * 16 + m16)) * SS + sh;

  // coalesced mask staging coords: thread t -> row t>>5, cols (t&31)*4..+4
  const int mrow_st = t >> 5;
  const int* mgbase = mask + ((size_t)(n * LL + l0 + mrow_st)) * SS + (t & 31) * 4;

  f32x4 acc_o = {0.f, 0.f, 0.f, 0.f};
  float rsum = 0.f;
  bf16x4 stash[16];  // exp'd scores, 4 consecutive s per chunk (static idx -> regs)

  // mask reg pipeline, depth 2: global -> reg (1 chunk) -> LDS (1 chunk) -> use
  int4 mreg[2];
  mreg[0] = *(const int4*)(mgbase + 0 * 128);    // m(0)
  mreg[1] = *(const int4*)(mgbase + 1 * 128);    // m(1)

  // K fragment ping-pong
  bf16x8 kpa0, kpa1, kpb0, kpb1;
  {
    const __bf16* kr = kbase + (size_t)(w * 16 + m16) * DD;
    kpa0 = *(const bf16x8*)(kr + quad * 8);
    kpa1 = *(const bf16x8*)(kr + 32 + quad * 8);
  }

  // prologue: stage m(0) into LDS buf 0
  {
    const int4 m = mreg[0];
    mb_lds[0][mrow_st][t & 31] = (unsigned)((m.x != 0) | ((m.y != 0) << 8) |
                                            ((m.z != 0) << 16) | ((m.w != 0) << 24));
  }
  asm volatile("s_waitcnt lgkmcnt(0)" ::: "memory");
  __builtin_amdgcn_s_barrier();

#pragma unroll
  for (int c = 0; c < 16; ++c) {
    const int sc = c * 128;
    // ---- global loads in consumption order ----
    // (1) Vt frags: consumed this chunk, right after the barrier
    bf16x8 bv0 = *(const bf16x8*)(vrow + sc + quad * 8);
    bf16x8 bv1 = *(const bf16x8*)(vrow + sc + 32 + quad * 8);
    // (2) K for chunk c+1: consumed next chunk (QK)
    if (c + 1 < 16) {
      const __bf16* kr = kbase + (size_t)(sc + 128 + w * 16 + m16) * DD;
      if (c & 1) {
        kpa0 = *(const bf16x8*)(kr + quad * 8);
        kpa1 = *(const bf16x8*)(kr + 32 + quad * 8);
      } else {
        kpb0 = *(const bf16x8*)(kr + quad * 8);
        kpb1 = *(const bf16x8*)(kr + 32 + quad * 8);
      }
    }
    // (3) mask(c+2) global -> reg (coalesced 512B runs; consumed next chunk)
    if (c + 2 < 16) mreg[c & 1] = *(const int4*)(mgbase + (size_t)(c + 2) * 128);
    // (4) stage m(c+1) reg -> LDS (loaded during chunk c-1; in flight 1 chunk)
    if (c + 1 < 16) {
      const int4 m = mreg[(c + 1) & 1];
      mb_lds[(c + 1) & 1][mrow_st][t & 31] =
          (unsigned)((m.x != 0) | ((m.y != 0) << 8) | ((m.z != 0) << 16) |
                     ((m.w != 0) << 24));
    }
    // (5) this chunk's mask flags for owner lane: one uint = 4 flag bytes
    const unsigned mu = mb_lds[c & 1][m16][w * 4 + quad];
    // QK transposed: D[row=quad*4+r -> s][col=m16 -> l]
    const bf16x8 kb0 = (c & 1) ? kpb0 : kpa0;
    const bf16x8 kb1 = (c & 1) ? kpb1 : kpa1;
    __builtin_amdgcn_s_setprio(1);  // compute cluster: preempt other blocks' staging
    f32x4 acc = {0.f, 0.f, 0.f, 0.f};
    acc = __builtin_amdgcn_mfma_f32_16x16x32_bf16(kb0, aq0, acc, 0, 0, 0);
    acc = __builtin_amdgcn_mfma_f32_16x16x32_bf16(kb1, aq1, acc, 0, 0, 0);
    float e0 = (mu & 0x1u) ? __expf(acc[0]) : 0.f;
    float e1 = (mu & 0x100u) ? __expf(acc[1]) : 0.f;
    float e2 = (mu & 0x10000u) ? __expf(acc[2]) : 0.f;
    float e3 = (mu & 0x1000000u) ? __expf(acc[3]) : 0.f;
    __builtin_amdgcn_s_setprio(0);
    rsum += (e0 + e1) + (e2 + e3);
    bf16x4 sv;
    sv[0] = (__bf16)e0;
    sv[1] = (__bf16)e1;
    sv[2] = (__bf16)e2;
    sv[3] = (__bf16)e3;
    stash[c] = sv;
    *(bf16x4*)(&e_lds[c & 1][m16][w * 16 + quad * 4]) = sv;
    // LDS-only fence + raw barrier (orders e_lds AND mb_lds writes; global
    // prefetches stay in flight — no vmcnt(0)).
    asm volatile("s_waitcnt lgkmcnt(0)" ::: "memory");
    __builtin_amdgcn_s_barrier();
    // PV: A = E[l][s-half], B = Vt[v-group][s-half]
    __builtin_amdgcn_s_setprio(1);
    bf16x8 ae0 = *(const bf16x8*)(&e_lds[c & 1][m16][sh + quad * 8]);
    bf16x8 ae1 = *(const bf16x8*)(&e_lds[c & 1][m16][sh + 32 + quad * 8]);
    acc_o = __builtin_amdgcn_mfma_f32_16x16x32_bf16(ae0, bv0, acc_o, 0, 0, 0);
    acc_o = __builtin_amdgcn_mfma_f32_16x16x32_bf16(ae1, bv1, acc_o, 0, 0, 0);
    __builtin_amdgcn_s_setprio(0);
    // dbuf proofs: e_lds[c&1]/mb_lds[(c+1)&1] rewritten only after the barrier
    // that follows their last reads (std double-buffer argument).
  }

  // rowsum: reduce quads within wave, publish, combine across waves
  rsum += __shfl_xor(rsum, 16);
  rsum += __shfl_xor(rsum, 32);
  if (quad == 0) rs_lds[w][m16] = rsum;
  if (w >= 4) {
#pragma unroll
    for (int r = 0; r < 4; ++r) acc_red[vg][quad * 4 + r][m16] = acc_o[r];
  }
  __syncthreads();

  float tot = 0.f;
#pragma unroll
  for (int ww = 0; ww < 8; ++ww) tot += rs_lds[ww][m16];
  const float inv_s = 1.0f / tot;  // row l = l0+m16
  if (t < 16) inv_row[t] = inv_s;  // t<16 -> w=0, m16=t

  // out_value: lower s-half waves combine pair partials
  if (w < 4) {
#pragma unroll
    for (int r = 0; r < 4; ++r) {
      const int row = quad * 4 + r;
      float tr = 0.f;
#pragma unroll
      for (int ww = 0; ww < 8; ++ww) tr += rs_lds[ww][row];
      const float o = (acc_o[r] + acc_red[vg][row][m16]) / tr;
      out_val[((size_t)(n * LL + l0 + row)) * DD + vg * 16 + m16] = o;
    }
  }
  __syncthreads();  // inv_row visible; rs/acc_red reads done

  // ---- score epilogue: LDS transpose -> fully coalesced stores ----
  // 4 groups of 512 s-cols; store thread t -> row t>>5, col (t&31)*4 + i*128:
  // 32 consecutive lanes write 512B contiguous per instruction.
  const int erow = t >> 5;
  const int ecol = (t & 31) * 4;
  const float einv = inv_row[erow];
  float* obase = out_score + ((size_t)(n * LL + l0 + erow)) * SS;
#pragma unroll
  for (int g = 0; g < 4; ++g) {
#pragma unroll
    for (int i = 0; i < 4; ++i) {
      *(bf16x4*)(&ep_buf[m16][i * 128 + w * 16 + quad * 4]) = stash[g * 4 + i];
    }
    asm volatile("s_waitcnt lgkmcnt(0)" ::: "memory");
    __builtin_amdgcn_s_barrier();
#pragma unroll
    for (int i = 0; i < 4; ++i) {
      const bf16x4 ev = *(const bf16x4*)(&ep_buf[erow][ecol + i * 128]);
      float4 o;
      o.x = (float)ev[0] * einv;
      o.y = (float)ev[1] * einv;
      o.z = (float)ev[2] * einv;
      o.w = (float)ev[3] * einv;
      *(float4*)(obase + g * 512 + ecol + i * 128) = o;
    }
    asm volatile("s_waitcnt lgkmcnt(0)" ::: "memory");
    __builtin_amdgcn_s_barrier();  // reads done before next group's writes
  }
}

extern "C" void kernel_launch(void* const* d_in, const int* in_sizes, int n_in,
                              void* d_out, int out_size, void* d_ws, size_t ws_size,
                              hipStream_t stream) {
  const float* q = (const float*)d_in[0];
  const float* k = (const float*)d_in[1];
  const float* v = (const float*)d_in[2];
  const int* mask = (const int*)d_in[3];  // harness materializes bool as int32

  float* out_val = (float*)d_out;                       // [8,2048,64]
  float* out_score = out_val + (size_t)NB * LL * DD;    // [8,2048,2048]

  __bf16* Qb = (__bf16*)d_ws;                  // 2 MB
  __bf16* Kb = Qb + (size_t)NB * LL * DD;      // 2 MB
  __bf16* Vt = Kb + (size_t)NB * SS * DD;      // 2 MB (transposed [n][v][s])

  prep_all<<<dim3(NORM_BLOCKS + VT_BLOCKS), dim3(256), 0, stream>>>(q, k, v, Qb, Kb, Vt);
  attn_main<<<dim3(LL / 16, NB), dim3(512), 0, stream>>>(Qb, Kb, Vt, mask, out_val, out_score);
}

// Round 13
// 277.590 us; speedup vs baseline: 1.1494x; 1.0131x over previous
//
#include <hip/hip_runtime.h>
#include <hip/hip_bf16.h>
#include <math.h>

// Cosine attention, n=8, L=S=2048, d=v=64.
// out0 = softmax((q^·k^T)/8) @ V  [8,2048,64]; out1 = softmax scores [8,2048,2048]
// |score| <= 1/8 (unit vectors) -> exp in [0.88,1.13] -> no running max needed.
//
// v13 = best-measured configuration, locked in.
//   attn_main = r8 VERBATIM (99us attn / 278us total best). r12 isolated
//   setprio at -5% (lockstep blocks: priority starves staging waves) -> removed.
//   prep stays fused (r12: neutral, one less launch).
//   Session ledger: harness-fixed ~164us (invariant across all 13 runs),
//   prep ~14us, attn ~99us floor reproduced under five scheduling regimes.
//   Falsified mechanisms for the remaining attn gap (byte-floor ~45us):
//   barrier vmcnt drain (r6/r7), mask HBM latency depth 2->4 (r10), counted
//   vmcnt issue order (r7), L2 pinning (r6), R=2 K/V reuse (r11, L3-footprint
//   blowup), streamed stores (r5/r9, recompute cost), setprio (r12).
// Mask arrives as int32 (harness materializes bool as int) — NOT bytes.

typedef __bf16 bf16x8 __attribute__((ext_vector_type(8)));
typedef __bf16 bf16x4 __attribute__((ext_vector_type(4)));
typedef float f32x4 __attribute__((ext_vector_type(4)));

#define NB 8
#define LL 2048
#define SS 2048
#define DD 64
#define NORM_BLOCKS ((NB * LL * 2) / 4)
#define VT_BLOCKS (NB * (SS / 64))

// ---- fused prep: [0,8192) Q/K norm | [8192,8448) V transpose ----
__global__ __launch_bounds__(256) void prep_all(const float* __restrict__ q,
                                                const float* __restrict__ k,
                                                const float* __restrict__ v,
                                                __bf16* __restrict__ Qb,
                                                __bf16* __restrict__ Kb,
                                                __bf16* __restrict__ Vt) {
  __shared__ __bf16 tile[64][72];  // Vt branch only
  const int bid = blockIdx.x;
  const int t = threadIdx.x;

  if (bid < NORM_BLOCKS) {
    // L2-normalize Q (fold 1/8) and K rows, cast to bf16; one wave per row.
    const int w = t >> 6, lane = t & 63;
    const int r = bid * 4 + w;
    const float* src;
    __bf16* dst;
    float extra;
    if (r < NB * LL) {
      src = q + (size_t)r * DD;
      dst = Qb + (size_t)r * DD;
      extra = 0.125f;  // fold 1/sqrt(64) into Q
    } else {
      int rk = r - NB * LL;
      src = k + (size_t)rk * DD;
      dst = Kb + (size_t)rk * DD;
      extra = 1.0f;
    }
    float x = src[lane];
    float ss = x * x;
    ss += __shfl_xor(ss, 1);
    ss += __shfl_xor(ss, 2);
    ss += __shfl_xor(ss, 4);
    ss += __shfl_xor(ss, 8);
    ss += __shfl_xor(ss, 16);
    ss += __shfl_xor(ss, 32);
    float nrm = sqrtf(ss);
    float sc = extra / fmaxf(nrm, 1e-12f);
    dst[lane] = (__bf16)(x * sc);
  } else {
    // V [n][s][v] f32 -> Vt [n][v][s] bf16, 64x64 LDS tiles.
    const int vb = bid - NORM_BLOCKS;  // 0..255
    const int n = vb >> 5;
    const int s0 = (vb & 31) * 64;
#pragma unroll
    for (int it = 0; it < 4; ++it) {
      int idx = t + it * 256;
      int s = idx >> 4, c = idx & 15;
      float4 f = *(const float4*)(v + ((size_t)(n * SS + s0 + s)) * DD + c * 4);
      tile[s][c * 4 + 0] = (__bf16)f.x;
      tile[s][c * 4 + 1] = (__bf16)f.y;
      tile[s][c * 4 + 2] = (__bf16)f.z;
      tile[s][c * 4 + 3] = (__bf16)f.w;
    }
    __syncthreads();
#pragma unroll
    for (int it = 0; it < 4; ++it) {
      int idx = t + it * 256;
      int vv = idx >> 4, c = idx & 15;
      bf16x4 o;
      o[0] = tile[c * 4 + 0][vv];
      o[1] = tile[c * 4 + 1][vv];
      o[2] = tile[c * 4 + 2][vv];
      o[3] = tile[c * 4 + 3][vv];
      *(bf16x4*)(Vt + ((size_t)(n * DD + vv)) * SS + s0 + c * 4) = o;
    }
  }
}

// ---- main: 16 L-rows per block, 8 waves (512 thr), S streamed in 128-col chunks ----
__global__ __launch_bounds__(512, 4) void attn_main(const __bf16* __restrict__ Qb,
                                                    const __bf16* __restrict__ Kb,
                                                    const __bf16* __restrict__ Vt,
                                                    const int* __restrict__ mask,
                                                    float* __restrict__ out_val,
                                                    float* __restrict__ out_score) {
  __shared__ __bf16 e_lds[2][16][136];     // E chunk, row = l, col = s-in-chunk
  __shared__ unsigned mb_lds[2][16][33];   // packed mask (4 flag-bytes per uint)
  __shared__ float rs_lds[8][16];          // per-wave row-sum partials
  __shared__ float acc_red[4][16][17];     // PV partial exchange
  __shared__ float inv_row[16];            // 1/rowsum for epilogue threads
  __shared__ __bf16 ep_buf[16][520];       // epilogue transpose buffer (512+8 pad)

  const int n = blockIdx.y;
  const int l0 = blockIdx.x * 16;

  const int t = threadIdx.x;
  const int w = t >> 6;
  const int lane = t & 63;
  const int m16 = lane & 15;
  const int quad = lane >> 4;
  const int vg = w & 3;            // PV v-group
  const int sh = (w >> 2) * 64;    // PV s-half within chunk

  // Q fragment (B operand of transposed QK): B[n=m16][k=quad*8+j] = Q[l0+m16][k]
  const __bf16* qrow = Qb + ((size_t)(n * LL + l0 + m16)) * DD;
  bf16x8 aq0 = *(const bf16x8*)(qrow + quad * 8);
  bf16x8 aq1 = *(const bf16x8*)(qrow + 32 + quad * 8);

  const __bf16* kbase = Kb + (size_t)n * SS * DD;
  const __bf16* vrow = Vt + ((size_t)(n * DD + vg * 16 + m16)) * SS + sh;

  // coalesced mask staging coords: thread t -> row t>>5, cols (t&31)*4..+4
  const int mrow_st = t >> 5;
  const int* mgbase = mask + ((size_t)(n * LL + l0 + mrow_st)) * SS + (t & 31) * 4;

  f32x4 acc_o = {0.f, 0.f, 0.f, 0.f};
  float rsum = 0.f;
  bf16x4 stash[16];  // exp'd scores, 4 consecutive s per chunk (static idx -> regs)

  // mask reg pipeline, depth 2: global -> reg (1 chunk) -> LDS (1 chunk) -> use
  int4 mreg[2];
  mreg[0] = *(const int4*)(mgbase + 0 * 128);    // m(0)
  mreg[1] = *(const int4*)(mgbase + 1 * 128);    // m(1)

  // K fragment ping-pong
  bf16x8 kpa0, kpa1, kpb0, kpb1;
  {
    const __bf16* kr = kbase + (size_t)(w * 16 + m16) * DD;
    kpa0 = *(const bf16x8*)(kr + quad * 8);
    kpa1 = *(const bf16x8*)(kr + 32 + quad * 8);
  }

  // prologue: stage m(0) into LDS buf 0
  {
    const int4 m = mreg[0];
    mb_lds[0][mrow_st][t & 31] = (unsigned)((m.x != 0) | ((m.y != 0) << 8) |
                                            ((m.z != 0) << 16) | ((m.w != 0) << 24));
  }
  asm volatile("s_waitcnt lgkmcnt(0)" ::: "memory");
  __builtin_amdgcn_s_barrier();

#pragma unroll
  for (int c = 0; c < 16; ++c) {
    const int sc = c * 128;
    // ---- global loads in consumption order ----
    // (1) Vt frags: consumed this chunk, right after the barrier
    bf16x8 bv0 = *(const bf16x8*)(vrow + sc + quad * 8);
    bf16x8 bv1 = *(const bf16x8*)(vrow + sc + 32 + quad * 8);
    // (2) K for chunk c+1: consumed next chunk (QK)
    if (c + 1 < 16) {
      const __bf16* kr = kbase + (size_t)(sc + 128 + w * 16 + m16) * DD;
      if (c & 1) {
        kpa0 = *(const bf16x8*)(kr + quad * 8);
        kpa1 = *(const bf16x8*)(kr + 32 + quad * 8);
      } else {
        kpb0 = *(const bf16x8*)(kr + quad * 8);
        kpb1 = *(const bf16x8*)(kr + 32 + quad * 8);
      }
    }
    // (3) mask(c+2) global -> reg (coalesced 512B runs; consumed next chunk)
    if (c + 2 < 16) mreg[c & 1] = *(const int4*)(mgbase + (size_t)(c + 2) * 128);
    // (4) stage m(c+1) reg -> LDS (loaded during chunk c-1; in flight 1 chunk)
    if (c + 1 < 16) {
      const int4 m = mreg[(c + 1) & 1];
      mb_lds[(c + 1) & 1][mrow_st][t & 31] =
          (unsigned)((m.x != 0) | ((m.y != 0) << 8) | ((m.z != 0) << 16) |
                     ((m.w != 0) << 24));
    }
    // (5) this chunk's mask flags for owner lane: one uint = 4 flag bytes
    const unsigned mu = mb_lds[c & 1][m16][w * 4 + quad];
    // QK transposed: D[row=quad*4+r -> s][col=m16 -> l]
    const bf16x8 kb0 = (c & 1) ? kpb0 : kpa0;
    const bf16x8 kb1 = (c & 1) ? kpb1 : kpa1;
    f32x4 acc = {0.f, 0.f, 0.f, 0.f};
    acc = __builtin_amdgcn_mfma_f32_16x16x32_bf16(kb0, aq0, acc, 0, 0, 0);
    acc = __builtin_amdgcn_mfma_f32_16x16x32_bf16(kb1, aq1, acc, 0, 0, 0);
    float e0 = (mu & 0x1u) ? __expf(acc[0]) : 0.f;
    float e1 = (mu & 0x100u) ? __expf(acc[1]) : 0.f;
    float e2 = (mu & 0x10000u) ? __expf(acc[2]) : 0.f;
    float e3 = (mu & 0x1000000u) ? __expf(acc[3]) : 0.f;
    rsum += (e0 + e1) + (e2 + e3);
    bf16x4 sv;
    sv[0] = (__bf16)e0;
    sv[1] = (__bf16)e1;
    sv[2] = (__bf16)e2;
    sv[3] = (__bf16)e3;
    stash[c] = sv;
    *(bf16x4*)(&e_lds[c & 1][m16][w * 16 + quad * 4]) = sv;
    // LDS-only fence + raw barrier (orders e_lds AND mb_lds writes; global
    // prefetches stay in flight — no vmcnt(0)).
    asm volatile("s_waitcnt lgkmcnt(0)" ::: "memory");
    __builtin_amdgcn_s_barrier();
    // PV: A = E[l][s-half], B = Vt[v-group][s-half]
    bf16x8 ae0 = *(const bf16x8*)(&e_lds[c & 1][m16][sh + quad * 8]);
    bf16x8 ae1 = *(const bf16x8*)(&e_lds[c & 1][m16][sh + 32 + quad * 8]);
    acc_o = __builtin_amdgcn_mfma_f32_16x16x32_bf16(ae0, bv0, acc_o, 0, 0, 0);
    acc_o = __builtin_amdgcn_mfma_f32_16x16x32_bf16(ae1, bv1, acc_o, 0, 0, 0);
    // dbuf proofs: e_lds[c&1]/mb_lds[(c+1)&1] rewritten only after the barrier
    // that follows their last reads (std double-buffer argument).
  }

  // rowsum: reduce quads within wave, publish, combine across waves
  rsum += __shfl_xor(rsum, 16);
  rsum += __shfl_xor(rsum, 32);
  if (quad == 0) rs_lds[w][m16] = rsum;
  if (w >= 4) {
#pragma unroll
    for (int r = 0; r < 4; ++r) acc_red[vg][quad * 4 + r][m16] = acc_o[r];
  }
  __syncthreads();

  float tot = 0.f;
#pragma unroll
  for (int ww = 0; ww < 8; ++ww) tot += rs_lds[ww][m16];
  const float inv_s = 1.0f / tot;  // row l = l0+m16
  if (t < 16) inv_row[t] = inv_s;  // t<16 -> w=0, m16=t

  // out_value: lower s-half waves combine pair partials
  if (w < 4) {
#pragma unroll
    for (int r = 0; r < 4; ++r) {
      const int row = quad * 4 + r;
      float tr = 0.f;
#pragma unroll
      for (int ww = 0; ww < 8; ++ww) tr += rs_lds[ww][row];
      const float o = (acc_o[r] + acc_red[vg][row][m16]) / tr;
      out_val[((size_t)(n * LL + l0 + row)) * DD + vg * 16 + m16] = o;
    }
  }
  __syncthreads();  // inv_row visible; rs/acc_red reads done

  // ---- score epilogue: LDS transpose -> fully coalesced stores ----
  // 4 groups of 512 s-cols; store thread t -> row t>>5, col (t&31)*4 + i*128:
  // 32 consecutive lanes write 512B contiguous per instruction.
  const int erow = t >> 5;
  const int ecol = (t & 31) * 4;
  const float einv = inv_row[erow];
  float* obase = out_score + ((size_t)(n * LL + l0 + erow)) * SS;
#pragma unroll
  for (int g = 0; g < 4; ++g) {
#pragma unroll
    for (int i = 0; i < 4; ++i) {
      *(bf16x4*)(&ep_buf[m16][i * 128 + w * 16 + quad * 4]) = stash[g * 4 + i];
    }
    asm volatile("s_waitcnt lgkmcnt(0)" ::: "memory");
    __builtin_amdgcn_s_barrier();
#pragma unroll
    for (int i = 0; i < 4; ++i) {
      const bf16x4 ev = *(const bf16x4*)(&ep_buf[erow][ecol + i * 128]);
      float4 o;
      o.x = (float)ev[0] * einv;
      o.y = (float)ev[1] * einv;
      o.z = (float)ev[2] * einv;
      o.w = (float)ev[3] * einv;
      *(float4*)(obase + g * 512 + ecol + i * 128) = o;
    }
    asm volatile("s_waitcnt lgkmcnt(0)" ::: "memory");
    __builtin_amdgcn_s_barrier();  // reads done before next group's writes
  }
}

extern "C" void kernel_launch(void* const* d_in, const int* in_sizes, int n_in,
                              void* d_out, int out_size, void* d_ws, size_t ws_size,
                              hipStream_t stream) {
  const float* q = (const float*)d_in[0];
  const float* k = (const float*)d_in[1];
  const float* v = (const float*)d_in[2];
  const int* mask = (const int*)d_in[3];  // harness materializes bool as int32

  float* out_val = (float*)d_out;                       // [8,2048,64]
  float* out_score = out_val + (size_t)NB * LL * DD;    // [8,2048,2048]

  __bf16* Qb = (__bf16*)d_ws;                  // 2 MB
  __bf16* Kb = Qb + (size_t)NB * LL * DD;      // 2 MB
  __bf16* Vt = Kb + (size_t)NB * SS * DD;      // 2 MB (transposed [n][v][s])

  prep_all<<<dim3(NORM_BLOCKS + VT_BLOCKS), dim3(256), 0, stream>>>(q, k, v, Qb, Kb, Vt);
  attn_main<<<dim3(LL / 16, NB), dim3(512), 0, stream>>>(Qb, Kb, Vt, mask, out_val, out_score);
}